// Round 6
// baseline (916.940 us; speedup 1.0000x reference)
//
#include <hip/hip_runtime.h>

// TrPredictor round 18 = r17 + (a) VW2 block-interleave (restores b64 write
// coalescing lost in r17's element-interleave: 8-way-conflict u16 scatters ->
// 2 merged b64 writes/tile) + (b) X fully register-resident via embedding
// permutation pi(quad*8+j) = quad*4+(j&3)+16*(j>=4).
// pi makes each lane's MFMA C-layout ownership == its A/B k-slot set, so:
//   - embedding loads go straight to 4 packed-bf16 u32 regs per tile
//   - LN (stats already register-fused via shfl) normalizes in-register
//   - Phase C/E epilogues RMW registers; X LDS array deleted entirely
// pi applied to weight-fragment input rows at prep (wq/wk/wvo/w1); w2 and all
// output-dim orders unchanged. LDS = K2+VW2 = 30464 B -> 4 blocks/CU if
// VGPR<=128. Head: one X dump to LDS at the end.

#define SS   201
#define SP   208
#define NMT  13
#define EE   32
#define HIDN 512
#define NTRL 4
#define CWN  16
#define BB   4096
#define K2ST 20     // u32 row stride (80 B): b128-aligned reads at bank floor
#define VWST 216    // u16 row stride (432 B): b128-aligned, bank floor

#define VW2_OFF  16640   // K2: 208*80 = 16640 B at offset 0
#define SMEM_SZ  30464   // VW2: 32*432 = 13824 B

#define WS_FRAG  0        // 288 tiles x 1024 B; per layer: 0,1=q 2,3=k 4,5=wvo 6,7=unused
#define WS_BIAS  294912
#define WS_B1    299008
#define WS_FIN   307200
#define L2E      1.4426950408889634f
#define QCE      0.2550546813f   // (1/sqrt(32)) * log2(e)

typedef unsigned short u16;
typedef unsigned int   u32;
typedef short bf16x4 __attribute__((ext_vector_type(4)));
typedef short bf16x8 __attribute__((ext_vector_type(8)));
typedef float f32x4  __attribute__((ext_vector_type(4)));
typedef float f32x2  __attribute__((ext_vector_type(2)));

__device__ __forceinline__ f32x4 MF(bf16x8 a, bf16x8 b, f32x4 c){
  return __builtin_amdgcn_mfma_f32_16x16x32_bf16(a, b, c, 0, 0, 0);
}
__device__ __forceinline__ float bf2f(u16 u){ return __uint_as_float(((u32)u)<<16); }
__device__ __forceinline__ u16 f2bf(float f){            // exact RNE (cold paths)
  u32 u = __float_as_uint(f);
  u += 0x7fffu + ((u>>16)&1u);
  return (u16)(u>>16);
}
__device__ __forceinline__ u32 pk2bf(f32x2 v){
#if defined(__has_builtin) && __has_builtin(__builtin_amdgcn_cvt_pk_bf16_f32)
  auto r = __builtin_amdgcn_cvt_pk_bf16_f32(v.x, v.y);
  u32 u; __builtin_memcpy(&u, &r, 4); return u;
#else
  return ((__float_as_uint(v.x)+0x8000u)>>16) | ((__float_as_uint(v.y)+0x8000u) & 0xffff0000u);
#endif
}
__device__ __forceinline__ f32x2 upk2(u32 d){
  return f32x2{ __uint_as_float(d<<16), __uint_as_float(d & 0xffff0000u) };
}
template<bool F32>
__device__ __forceinline__ float ldv(const void* p, int i){
  if (F32) return ((const float*)p)[i];
  return bf2f(((const u16*)p)[i]);
}
template<bool F32>
__device__ __forceinline__ u16 ldbf(const void* p, int i){
  if (F32) return f2bf(((const float*)p)[i]);
  return ((const u16*)p)[i];
}
__device__ __forceinline__ bf16x8 cat44(bf16x4 lo, bf16x4 hi){
  bf16x8 r = {lo[0],lo[1],lo[2],lo[3],hi[0],hi[1],hi[2],hi[3]};
  return r;
}
__device__ __forceinline__ bf16x8 mk8(u32 a0, u32 a1, u32 a2, u32 a3){
  u32 t[4] = {a0,a1,a2,a3};
  bf16x8 r; __builtin_memcpy(&r, t, 16); return r;
}
// packed silu -> bf16 pair; arith f32x2 (v_pk_*_f32), trans scalar
__device__ __forceinline__ u32 spk(f32x2 z){
  const f32x2 nl2e2 = {-L2E, -L2E};
  const f32x2 one2  = {1.f, 1.f};
  f32x2 a = z * nl2e2;
  f32x2 e = { __builtin_amdgcn_exp2f(a.x), __builtin_amdgcn_exp2f(a.y) };
  f32x2 d = one2 + e;
  f32x2 rc = { __builtin_amdgcn_rcpf(d.x), __builtin_amdgcn_rcpf(d.y) };
  f32x2 s = z * rc;
  return pk2bf(s);
}

__device__ __forceinline__ int sniff_bf16(const void* tok_emb, int tid){
  int sane = 0;
  if (tid < 64){
    u16 wd = ((const u16*)tok_emb)[tid];
    int e = (wd >> 7) & 0xFF;
    sane = (e >= 100 && e <= 140) ? 1 : 0;
  }
  return (__syncthreads_count(sane) >= 52) ? 1 : 0;
}

// ===== pre-kernel 1: weight fragments (grid 288 x 64) =====
// r18: input (embedding) rows of wq/wk/wvo/w1 stored pi-permuted:
//   k-slot (quad, j) carries embedding pr = quad*4 + (j&3) + 16*(j>=4)
// wq pre-scaled by QCE. w2 keeps the r13 C-quad-pair hidden k-order.
template<bool F32>
__device__ __forceinline__ void frag_body(const void* wq, const void* wk,
    const void* wv, const void* wo, const void* w1, const void* w2, void* ws)
{
  int t = blockIdx.x;
  int l = t / 72, k = t % 72;
  int lane = threadIdx.x, l16 = lane & 15, quad = lane >> 4;
  bf16x8 v;
  if (k < 8){
    int mat = k >> 1, half = k & 1;
    if (mat == 2){
      // wvo = wv @ wo  (f32 accumulate, single bf16 rounding); pi on wv rows
      int col = half*16 + l16;
      #pragma unroll
      for (int j=0;j<8;j++){
        int pr = quad*4 + (j&3) + ((j&4)<<2);
        float acc = 0.f;
        for (int e=0;e<EE;e++)
          acc += ldv<F32>(wv, l*1024 + pr*32 + e) * ldv<F32>(wo, l*1024 + e*32 + col);
        v[j] = (short)f2bf(acc);
      }
    } else if (mat == 0){
      #pragma unroll
      for (int j=0;j<8;j++){
        int pr = quad*4 + (j&3) + ((j&4)<<2);
        v[j] = (short)f2bf(QCE * ldv<F32>(wq, l*1024 + pr*32 + half*16 + l16));
      }
    } else {
      const void* src = (mat==1)? wk : wo;
      #pragma unroll
      for (int j=0;j<8;j++){
        int pr = quad*4 + (j&3) + ((j&4)<<2);
        v[j] = (short)ldbf<F32>(src, l*1024 + pr*32 + half*16 + l16);
      }
    }
  } else if (k < 40){
    int nt = k - 8;
    #pragma unroll
    for (int j=0;j<8;j++){
      int pr = quad*4 + (j&3) + ((j&4)<<2);
      v[j] = (short)ldbf<F32>(w1, l*16384 + pr*512 + nt*16 + l16);
    }
  } else {
    int kc = (k-40)>>1, nh = (k-40)&1;
    #pragma unroll
    for (int j=0;j<8;j++){
      int hh = kc*32 + ((j&4) ? 16 : 0) + quad*4 + (j&3);
      v[j] = (short)ldbf<F32>(w2, l*16384 + hh*32 + nh*16 + l16);
    }
  }
  *(bf16x8*)((char*)ws + WS_FRAG + t*1024 + lane*16) = v;
}

__global__ __launch_bounds__(64) void fmt_frags(
    const void* __restrict__ tok_emb,
    const void* __restrict__ wq, const void* __restrict__ wk,
    const void* __restrict__ wv, const void* __restrict__ wo,
    const void* __restrict__ w1, const void* __restrict__ w2,
    void* __restrict__ ws)
{
  if (sniff_bf16(tok_emb, threadIdx.x)) frag_body<false>(wq,wk,wv,wo,w1,w2,ws);
  else                                  frag_body<true >(wq,wk,wv,wo,w1,w2,ws);
}

// ===== pre-kernel 2: biases / LN / head params (unchanged layouts) =====
template<bool F32>
__device__ __forceinline__ void bias_body(
    const void* bq, const void* bk, const void* bv, const void* wo, const void* bo,
    const void* ln1_g, const void* ln1_b, const void* ln2_g, const void* ln2_b,
    const void* b1, const void* b2,
    const void* lnf_g, const void* lnf_b, const void* wpen, const void* bpen,
    const void* wfan, const void* bfan, const void* wcal, const void* bcal,
    void* ws)
{
  int tid = threadIdx.x, idx = tid & 31, grp = tid >> 5;
  float* BW  = (float*)((char*)ws + WS_BIAS);
  float* BW1 = (float*)((char*)ws + WS_B1);
  float* FW  = (float*)((char*)ws + WS_FIN);
  for (int l=0;l<NTRL;l++){
    float v = 0.f;
    switch(grp){
      case 0: v = QCE * ldv<F32>(bq, l*32+idx); break;   // scaled with wq
      case 1: v = ldv<F32>(bk, l*32+idx); break;
      case 2: {
        float acc = ldv<F32>(bo, l*32+idx);
        for (int e=0;e<EE;e++) acc += ldv<F32>(bv, l*32+e) * ldv<F32>(wo, l*1024 + e*32 + idx);
        v = acc; break;
      }
      case 3: v = ldv<F32>(ln1_g, l*32+idx); break;
      case 4: v = ldv<F32>(ln1_b, l*32+idx); break;
      case 5: v = ldv<F32>(ln2_g, l*32+idx); break;
      case 6: v = ldv<F32>(ln2_b, l*32+idx); break;
      case 7: v = ldv<F32>(b2,   l*32+idx); break;
    }
    BW[l*256 + tid] = v;
  }
  for (int i=tid; i<NTRL*HIDN; i+=256) BW1[i] = ldv<F32>(b1, i);
  if (tid < 32){
    FW[tid]    = ldv<F32>(lnf_g, tid);
    FW[32+tid] = ldv<F32>(lnf_b, tid);
    FW[64+tid] = ldv<F32>(wpen, tid);
  }
  if (tid == 0) FW[96] = ldv<F32>(bpen, 0);
  if (tid < 16){ FW[97+tid] = ldv<F32>(wfan, tid); FW[113+tid] = ldv<F32>(bfan, tid); }
  if (tid < 128) FW[129+tid] = ldv<F32>(wcal, tid);
  if (tid < 8)   FW[257+tid] = ldv<F32>(bcal, tid);
}

__global__ __launch_bounds__(256) void fmt_bias(
    const void* __restrict__ tok_emb,
    const void* __restrict__ bq, const void* __restrict__ bk,
    const void* __restrict__ bv, const void* __restrict__ wo, const void* __restrict__ bo,
    const void* __restrict__ ln1_g, const void* __restrict__ ln1_b,
    const void* __restrict__ ln2_g, const void* __restrict__ ln2_b,
    const void* __restrict__ b1, const void* __restrict__ b2,
    const void* __restrict__ lnf_g, const void* __restrict__ lnf_b,
    const void* __restrict__ wpen, const void* __restrict__ bpen,
    const void* __restrict__ wfan, const void* __restrict__ bfan,
    const void* __restrict__ wcal, const void* __restrict__ bcal,
    void* __restrict__ ws)
{
  if (sniff_bf16(tok_emb, threadIdx.x))
    bias_body<false>(bq,bk,bv,wo,bo,ln1_g,ln1_b,ln2_g,ln2_b,b1,b2,
                     lnf_g,lnf_b,wpen,bpen,wfan,bfan,wcal,bcal,ws);
  else
    bias_body<true >(bq,bk,bv,wo,bo,ln1_g,ln1_b,ln2_g,ln2_b,b1,b2,
                     lnf_g,lnf_b,wpen,bpen,wfan,bfan,wcal,bcal,ws);
}

// ===== main kernel helpers =====
// LN-normalize the lane's 8 owned X values (packed bf16 regs) into a fragment.
// Pair p -> cols: p0:(q4,q4+1) p1:(q4+2,q4+3) p2:(16+q4,16+q4+1) p3:(16+q4+2,+3)
__device__ __forceinline__ bf16x8 nfrag_x(const u32* xp, float m, float rs,
                                          f32x4 ga, f32x4 gb, f32x4 ba, f32x4 bb){
  f32x2 m2 = {m, m}, rs2 = {rs, rs};
  u32 o[4];
  o[0] = pk2bf((upk2(xp[0]) - m2) * rs2 * f32x2{ga[0],ga[1]} + f32x2{ba[0],ba[1]});
  o[1] = pk2bf((upk2(xp[1]) - m2) * rs2 * f32x2{ga[2],ga[3]} + f32x2{ba[2],ba[3]});
  o[2] = pk2bf((upk2(xp[2]) - m2) * rs2 * f32x2{gb[0],gb[1]} + f32x2{bb[0],bb[1]});
  o[3] = pk2bf((upk2(xp[3]) - m2) * rs2 * f32x2{gb[2],gb[3]} + f32x2{bb[2],bb[3]});
  bf16x8 r; __builtin_memcpy(&r, o, 16);
  return r;
}

// reduce per-quad partials (8 cols each) to full-row mean/rsqrt in registers
__device__ __forceinline__ void red_stats(float ps, float pq, float& m, float& rs){
  ps += __shfl_xor(ps, 16); ps += __shfl_xor(ps, 32);
  pq += __shfl_xor(pq, 16); pq += __shfl_xor(pq, 32);
  m  = ps * (1.f/EE);
  rs = rsqrtf(pq * (1.f/EE) - m*m + 1e-5f);
}

template<bool F32>
__device__ __forceinline__ void tr_body(
    const int* seq, const int* expid,
    const void* tok_emb, const void* pos_emb,
    const void* ws, void* out, unsigned char* smem)
{
  u32* K2  = (u32*)smem;               // 208 rows x 20 u32 (pair-interleaved K)
  u16* VW2 = (u16*)(smem + VW2_OFF);   // 32 rows x 216 u16 (block-interleaved)

  const int tid  = threadIdx.x;
  const int lane = tid & 63, w = tid >> 6;
  const int l16  = lane & 15, quad = lane >> 4;
  const int b    = blockIdx.x;
  const f32x4 Z  = {0.f,0.f,0.f,0.f};

  // ---- embedding + positional straight into registers (pi-order) ----
  u32 xp[4][4];
  float m1[4], rs1[4], m2v[4], rs2v[4];
  {
    const int* srow = seq + b*SS;
    #pragma unroll
    for (int t=0;t<4;t++){
      int m = w + 4*t;
      if (m < NMT){
        int row = m*16 + l16;
        if (row < SS){
          int tok = srow[row];
          #pragma unroll
          for (int p=0;p<4;p++){
            int c = (p<2) ? (quad*4 + 2*p) : (16 + quad*4 + 2*(p-2));
            f32x2 v = { ldv<F32>(tok_emb, tok*EE + c)   + ldv<F32>(pos_emb, row*EE + c),
                        ldv<F32>(tok_emb, tok*EE + c+1) + ldv<F32>(pos_emb, row*EE + c+1) };
            xp[t][p] = pk2bf(v);
          }
        } else {
          xp[t][0]=0u; xp[t][1]=0u; xp[t][2]=0u; xp[t][3]=0u;
        }
        f32x2 s2 = {0.f,0.f}, q2 = {0.f,0.f};
        #pragma unroll
        for (int p=0;p<4;p++){ f32x2 x = upk2(xp[t][p]); s2 += x; q2 += x*x; }
        red_stats(s2.x+s2.y, q2.x+q2.y, m1[t], rs1[t]);
      }
    }
  }

  for (int l = 0; l < NTRL; ++l){
    const char* wsl = (const char*)ws + WS_FRAG + l*73728;
    const float* BW = (const float*)((const char*)ws + WS_BIAS) + l*256;
    bf16x8 bwq0 = *(const bf16x8*)(wsl + 0*1024 + lane*16);
    bf16x8 bwq1 = *(const bf16x8*)(wsl + 1*1024 + lane*16);
    bf16x8 bwk0 = *(const bf16x8*)(wsl + 2*1024 + lane*16);
    bf16x8 bwk1 = *(const bf16x8*)(wsl + 3*1024 + lane*16);
    bf16x8 bwv0 = *(const bf16x8*)(wsl + 4*1024 + lane*16);  // wvo halves
    bf16x8 bwv1 = *(const bf16x8*)(wsl + 5*1024 + lane*16);

    // ===== Phase B: K2, VW2 to LDS; Q^T packed in-register =====
    bf16x8 aq[4];
    {
      f32x4 ga = *(const f32x4*)(BW + 96 + quad*4);
      f32x4 gb = *(const f32x4*)(BW + 112 + quad*4);
      f32x4 ba = *(const f32x4*)(BW + 128 + quad*4);
      f32x4 bb = *(const f32x4*)(BW + 144 + quad*4);
      f32x4 bq0 = *(const f32x4*)(BW + quad*4);        // pre-scaled by QCE
      f32x4 bq1 = *(const f32x4*)(BW + 16 + quad*4);
      float bk0s = BW[32+l16], bk1s = BW[48+l16];
      f32x4 kc0 = {bk0s,bk0s,bk0s,bk0s};
      f32x4 kc1 = {bk1s,bk1s,bk1s,bk1s};
      #pragma unroll
      for (int t=0;t<4;t++){
        int m = w + 4*t;
        if (m < NMT){
          int m16 = m*16;
          bf16x8 an = nfrag_x(xp[t], m1[t], rs1[t], ga, gb, ba, bb);
          f32x4 ck0 = MF(an, bwk0, kc0), ck1 = MF(an, bwk1, kc1);
          #pragma unroll
          for (int r=0;r<4;r++)
            K2[(m16 + quad*4 + r)*K2ST + l16] = pk2bf(f32x2{ck0[r], ck1[r]});
          f32x4 cw0 = MF(an, bwv0, Z), cw1 = MF(an, bwv1, Z);
          {
            // block-interleave: pair p=m>>1 at u16 col p*32 + quad*8 + (m&1)*4;
            // tile 12 plain at 192 + quad*4. Contiguous r -> merged b64 writes.
            int base = (m == 12) ? (192 + quad*4)
                                 : ((m>>1)*32 + quad*8 + (m&1)*4);
            u32* p0 = (u32*)(VW2 + l16*VWST + base);
            u32* p1 = (u32*)(VW2 + (16+l16)*VWST + base);
            p0[0] = pk2bf(f32x2{cw0[0], cw0[1]});
            p0[1] = pk2bf(f32x2{cw0[2], cw0[3]});
            p1[0] = pk2bf(f32x2{cw1[0], cw1[1]});
            p1[1] = pk2bf(f32x2{cw1[2], cw1[3]});
          }
          f32x4 cq0 = MF(bwq0, an, bq0), cq1 = MF(bwq1, an, bq1);
          aq[t] = mk8(pk2bf(f32x2{cq0[0],cq1[0]}), pk2bf(f32x2{cq0[1],cq1[1]}),
                      pk2bf(f32x2{cq0[2],cq1[2]}), pk2bf(f32x2{cq0[3],cq1[3]}));
        }
      }
    }
    __syncthreads();   // K2/VW2 ready for all waves

    // ===== Phase C: attention via S^T + fused LN2 stats (register X RMW) =====
    {
      const u16* vb0 = VW2 + l16*VWST;
      const u16* vb1 = VW2 + (16+l16)*VWST;
      f32x4 ob0 = *(const f32x4*)(BW + 64 + quad*4);
      f32x4 ob1 = *(const f32x4*)(BW + 80 + quad*4);
      #pragma unroll
      for (int t=0;t<4;t++){
        int m = w + 4*t;
        if (m < NMT){
          u32 pbw[7][4];
          f32x2 pacc = {0.f, 0.f};
          #pragma unroll
          for (int c=0;c<6;c++){
            const bf16x8 ka = *(const bf16x8*)(K2 + ((2*c  )*16+l16)*K2ST + quad*4);
            const bf16x8 kb = *(const bf16x8*)(K2 + ((2*c+1)*16+l16)*K2ST + quad*4);
            f32x4 S0 = MF(ka, aq[t], Z);
            f32x4 S1 = MF(kb, aq[t], Z);
            f32x2 ea0 = { __builtin_amdgcn_exp2f(S0[0]), __builtin_amdgcn_exp2f(S0[1]) };
            f32x2 eb0 = { __builtin_amdgcn_exp2f(S0[2]), __builtin_amdgcn_exp2f(S0[3]) };
            f32x2 ea1 = { __builtin_amdgcn_exp2f(S1[0]), __builtin_amdgcn_exp2f(S1[1]) };
            f32x2 eb1 = { __builtin_amdgcn_exp2f(S1[2]), __builtin_amdgcn_exp2f(S1[3]) };
            pacc += (ea0 + eb0) + (ea1 + eb1);
            // BLOCK k-order: j0..3 = tile 2c keys q4..+3, j4..7 = tile 2c+1
            pbw[c][0] = pk2bf(ea0);
            pbw[c][1] = pk2bf(eb0);
            pbw[c][2] = pk2bf(ea1);
            pbw[c][3] = pk2bf(eb1);
          }
          { // tail: tile 12, keys 192..207 (201..207 masked)
            const bf16x8 ka = *(const bf16x8*)(K2 + (12*16+l16)*K2ST + quad*4);
            f32x4 S0 = MF(ka, aq[t], Z);
            f32x2 ea0 = { __builtin_amdgcn_exp2f(S0[0]), __builtin_amdgcn_exp2f(S0[1]) };
            f32x2 eb0 = { __builtin_amdgcn_exp2f(S0[2]), __builtin_amdgcn_exp2f(S0[3]) };
            int kb_ = quad*4;                 // keys 201..207: local idx >= 9
            if (kb_+0 >= 9) ea0.x = 0.f;
            if (kb_+1 >= 9) ea0.y = 0.f;
            if (kb_+2 >= 9) eb0.x = 0.f;
            if (kb_+3 >= 9) eb0.y = 0.f;
            pacc += ea0 + eb0;
            pbw[6][0] = pk2bf(ea0);
            pbw[6][1] = pk2bf(eb0);
            pbw[6][2] = 0u;
            pbw[6][3] = 0u;
          }
          float part = pacc.x + pacc.y;
          part += __shfl_xor(part, 16);
          part += __shfl_xor(part, 32);
          float inv = __builtin_amdgcn_rcpf(part);   // per query l16

          // PV: O^T = VW^T . P^T; block-interleaved b128 A-reads, tail dup
          f32x4 o0 = Z, o1 = Z;
          #pragma unroll
          for (int c=0;c<6;c++){
            bf16x8 A0 = *(const bf16x8*)(vb0 + c*32 + quad*8);
            bf16x8 A1 = *(const bf16x8*)(vb1 + c*32 + quad*8);
            bf16x8 B8 = mk8(pbw[c][0], pbw[c][1], pbw[c][2], pbw[c][3]);
            o0 = MF(A0, B8, o0);
            o1 = MF(A1, B8, o1);
          }
          {
            bf16x4 a0 = *(const bf16x4*)(vb0 + 192 + quad*4);
            bf16x4 a1 = *(const bf16x4*)(vb1 + 192 + quad*4);
            bf16x8 B8 = mk8(pbw[6][0], pbw[6][1], 0u, 0u);
            o0 = MF(cat44(a0, a0), B8, o0);   // upper A pairs with zero B
            o1 = MF(cat44(a1, a1), B8, o1);
          }

          // register X RMW + fused LN2 stats (pre-rounding f32 values)
          f32x2 r01 = f32x2{o0[0],o0[1]} * inv + (upk2(xp[t][0]) + f32x2{ob0[0],ob0[1]});
          f32x2 r23 = f32x2{o0[2],o0[3]} * inv + (upk2(xp[t][1]) + f32x2{ob0[2],ob0[3]});
          f32x2 s01 = f32x2{o1[0],o1[1]} * inv + (upk2(xp[t][2]) + f32x2{ob1[0],ob1[1]});
          f32x2 s23 = f32x2{o1[2],o1[3]} * inv + (upk2(xp[t][3]) + f32x2{ob1[2],ob1[3]});
          xp[t][0] = pk2bf(r01);
          xp[t][1] = pk2bf(r23);
          xp[t][2] = pk2bf(s01);
          xp[t][3] = pk2bf(s23);
          f32x2 ss = (r01 + r23) + (s01 + s23);
          f32x2 qq = r01*r01; qq += r23*r23; qq += s01*s01; qq += s23*s23;
          red_stats(ss.x+ss.y, qq.x+qq.y, m2v[t], rs2v[t]);
        }
      }
    }
    __syncthreads();   // all K2/VW2 reads done; next-layer B may overwrite

    // ===== Phase E: MLP register-resident, register X RMW, fused LN1 stats =====
    {
      f32x4 ga = *(const f32x4*)(BW + 160 + quad*4);
      f32x4 gb = *(const f32x4*)(BW + 176 + quad*4);
      f32x4 ba = *(const f32x4*)(BW + 192 + quad*4);
      f32x4 bb = *(const f32x4*)(BW + 208 + quad*4);
      bf16x8 anc[4];
      #pragma unroll
      for (int t=0;t<4;t++){
        int m = w + 4*t;
        if (m < NMT) anc[t] = nfrag_x(xp[t], m2v[t], rs2v[t], ga, gb, ba, bb);
      }
      f32x4 oacc[4][2];
      #pragma unroll
      for (int t=0;t<4;t++){ oacc[t][0] = Z; oacc[t][1] = Z; }
      const char* w1f = wsl + 8*1024;
      const char* w2f = wsl + 40*1024;
      const float* BW1 = (const float*)((const char*)ws + WS_B1) + l*HIDN;

      for (int hp = 0; hp < 16; ++hp){
        bf16x8 a1lo = *(const bf16x8*)(w1f + (2*hp  )*1024 + lane*16);
        bf16x8 a1hi = *(const bf16x8*)(w1f + (2*hp+1)*1024 + lane*16);
        bf16x8 a2e0 = *(const bf16x8*)(w2f + (hp*2  )*1024 + lane*16);
        bf16x8 a2e1 = *(const bf16x8*)(w2f + (hp*2+1)*1024 + lane*16);
        f32x4 b1q0 = *(const f32x4*)(BW1 + hp*32      + quad*4);
        f32x4 b1q1 = *(const f32x4*)(BW1 + hp*32 + 16 + quad*4);
        #pragma unroll
        for (int t=0;t<4;t++){
          int m = w + 4*t;
          if (m < NMT){
            f32x4 z0 = MF(a1lo, anc[t], b1q0);   // bias in C (exact)
            f32x4 z1 = MF(a1hi, anc[t], b1q1);
            bf16x8 H8 = mk8(spk(f32x2{z0[0], z0[1]}), spk(f32x2{z0[2], z0[3]}),
                            spk(f32x2{z1[0], z1[1]}), spk(f32x2{z1[2], z1[3]}));
            oacc[t][0] = MF(a2e0, H8, oacc[t][0]);
            oacc[t][1] = MF(a2e1, H8, oacc[t][1]);
          }
        }
      }

      f32x4 b2q0 = *(const f32x4*)(BW + 224 + quad*4);
      f32x4 b2q1 = *(const f32x4*)(BW + 240 + quad*4);
      #pragma unroll
      for (int t=0;t<4;t++){
        int m = w + 4*t;
        if (m < NMT){
          f32x2 r01 = f32x2{oacc[t][0][0], oacc[t][0][1]} + (upk2(xp[t][0]) + f32x2{b2q0[0], b2q0[1]});
          f32x2 r23 = f32x2{oacc[t][0][2], oacc[t][0][3]} + (upk2(xp[t][1]) + f32x2{b2q0[2], b2q0[3]});
          f32x2 s01 = f32x2{oacc[t][1][0], oacc[t][1][1]} + (upk2(xp[t][2]) + f32x2{b2q1[0], b2q1[1]});
          f32x2 s23 = f32x2{oacc[t][1][2], oacc[t][1][3]} + (upk2(xp[t][3]) + f32x2{b2q1[2], b2q1[3]});
          xp[t][0] = pk2bf(r01);
          xp[t][1] = pk2bf(r23);
          xp[t][2] = pk2bf(s01);
          xp[t][3] = pk2bf(s23);
          f32x2 ss = (r01 + r23) + (s01 + s23);
          f32x2 qq = r01*r01; qq += r23*r23; qq += s01*s01; qq += s23*s23;
          red_stats(ss.x+ss.y, qq.x+qq.y, m1[t], rs1[t]);
        }
      }
    }
    // no barrier: E touches only registers + globals; next-layer B's LDS
    // writes are fenced by the post-C barrier above.
  }

  // ===== final head =====
  const float* FW = (const float*)((const char*)ws + WS_FIN);
  float* HB = (float*)(smem + VW2_OFF);        // VW2 region free after last C
  if (tid < 32){
    HB[tid]    = FW[tid];
    HB[32+tid] = FW[32+tid];
    HB[64+tid] = FW[64+tid];
  }
  // dump X registers (K2 region free after last C), stride 18 u32
  u32* hd = (u32*)smem;
  #pragma unroll
  for (int t=0;t<4;t++){
    int m = w + 4*t;
    if (m < NMT){
      u32* hr = hd + (m*16 + l16)*18;
      hr[quad*2]     = xp[t][0];
      hr[quad*2+1]   = xp[t][1];
      hr[8+quad*2]   = xp[t][2];
      hr[8+quad*2+1] = xp[t][3];
    }
  }
  __syncthreads();
  float part = 0.f;
  if (tid < SS){
    const u32* row = hd + tid*18;
    f32x2 v[16]; f32x2 s2 = {0.f,0.f};
    #pragma unroll
    for (int i=0;i<16;i++){ f32x2 p = upk2(row[i]); v[i] = p; s2 += p; }
    float m = (s2.x+s2.y) * (1.f/EE);
    f32x2 m2 = {m,m};
    f32x2 var2 = {0.f,0.f};
    #pragma unroll
    for (int i=0;i<16;i++){ f32x2 d = v[i]-m2; var2 += d*d; }
    float rs = rsqrtf((var2.x+var2.y)*(1.f/EE) + 1e-5f);
    f32x2 rs2 = {rs, rs};
    f32x2 dot2 = {0.f,0.f};
    #pragma unroll
    for (int i=0;i<16;i++){
      f32x2 g  = {HB[2*i], HB[2*i+1]};
      f32x2 bb = {HB[32+2*i], HB[33+2*i]};
      f32x2 wp = {HB[64+2*i], HB[65+2*i]};
      dot2 += ((v[i]-m2)*rs2*g + bb) * wp;
    }
    part = dot2.x + dot2.y + FW[96];
  }
  #pragma unroll
  for (int off=32; off; off>>=1) part += __shfl_xor(part, off);
  float* REDF = (float*)(smem + VW2_OFF + 512);
  __syncthreads();
  if (lane == 0) REDF[w] = part;
  __syncthreads();
  if (tid == 0){
    float u = REDF[0] + REDF[1] + REDF[2] + REDF[3];
    int ex = expid[b];
    float corr = FW[257+ex];
    #pragma unroll
    for (int c = 0; c < CWN; ++c){
      float pre = u * FW[97+c] + FW[113+c];
      pre = pre > 0.f ? pre : (__expf(pre) - 1.f);
      corr += pre * FW[129 + ex*CWN + c];
    }
    float res = corr + u;
    if (F32) ((float*)out)[b] = res;
    else     ((u16*)out)[b]  = f2bf(res);
  }
}

__global__ __launch_bounds__(256, 3) void tr_kernel(
    const int* __restrict__ seq, const int* __restrict__ expid,
    const void* __restrict__ tok_emb, const void* __restrict__ pos_emb,
    const void* __restrict__ ws, void* __restrict__ out)
{
  __shared__ __align__(16) unsigned char smem[SMEM_SZ];
  if (sniff_bf16(tok_emb, threadIdx.x))
    tr_body<false>(seq, expid, tok_emb, pos_emb, ws, out, smem);
  else
    tr_body<true >(seq, expid, tok_emb, pos_emb, ws, out, smem);
}

extern "C" void kernel_launch(void* const* d_in, const int* in_sizes, int n_in,
                              void* d_out, int out_size, void* d_ws, size_t ws_size,
                              hipStream_t stream)
{
  (void)in_sizes; (void)n_in; (void)ws_size; (void)out_size;
  const void* tok_emb = d_in[2];
  fmt_frags<<<dim3(288), dim3(64), 0, stream>>>(
      tok_emb, d_in[6], d_in[7], d_in[8], d_in[12], d_in[16], d_in[18], d_ws);
  fmt_bias<<<dim3(1), dim3(256), 0, stream>>>(
      tok_emb, d_in[9], d_in[10], d_in[11], d_in[12], d_in[13],
      d_in[4], d_in[5], d_in[14], d_in[15], d_in[17], d_in[19],
      d_in[20], d_in[21], d_in[22], d_in[23],
      d_in[24], d_in[25], d_in[26], d_in[27], d_ws);
  tr_kernel<<<dim3(BB), dim3(256), 0, stream>>>(
      (const int*)d_in[0], (const int*)d_in[1], tok_emb, d_in[3], d_ws, d_out);
}

// Round 7
// 858.517 us; speedup vs baseline: 1.0681x; 1.0681x over previous
//
#include <hip/hip_runtime.h>

// TrPredictor round 19 = r18 with the scratch-spill codegen bug fixed.
// r18 post-mortem: nfrag_x(xp[t], ...) passed a POINTER to the local xp array
// -> address-taken local defeats SROA -> xp[4][4] demoted to scratch ->
// 388 MB WRITE + 47 MB FETCH per dispatch, occupancy capped at 33%.
// Fix: xp is u32x4[4] (ext-vector, static indices only) and nfrag_x takes the
// pack BY VALUE. Everything else identical to r18 (passed, absmax 0.375):
// register-resident X via pi-permutation, block-interleaved VW2 (coalesced b64
// writes), K2 pair-interleave, 2 barriers/layer, register LN stats.

#define SS   201
#define SP   208
#define NMT  13
#define EE   32
#define HIDN 512
#define NTRL 4
#define CWN  16
#define BB   4096
#define K2ST 20     // u32 row stride (80 B): b128-aligned reads at bank floor
#define VWST 216    // u16 row stride (432 B): b128-aligned, bank floor

#define VW2_OFF  16640   // K2: 208*80 = 16640 B at offset 0
#define SMEM_SZ  30464   // VW2: 32*432 = 13824 B

#define WS_FRAG  0        // 288 tiles x 1024 B; per layer: 0,1=q 2,3=k 4,5=wvo 6,7=unused
#define WS_BIAS  294912
#define WS_B1    299008
#define WS_FIN   307200
#define L2E      1.4426950408889634f
#define QCE      0.2550546813f   // (1/sqrt(32)) * log2(e)

typedef unsigned short u16;
typedef unsigned int   u32;
typedef short bf16x4 __attribute__((ext_vector_type(4)));
typedef short bf16x8 __attribute__((ext_vector_type(8)));
typedef float f32x4  __attribute__((ext_vector_type(4)));
typedef float f32x2  __attribute__((ext_vector_type(2)));
typedef unsigned int u32x4 __attribute__((ext_vector_type(4)));

__device__ __forceinline__ f32x4 MF(bf16x8 a, bf16x8 b, f32x4 c){
  return __builtin_amdgcn_mfma_f32_16x16x32_bf16(a, b, c, 0, 0, 0);
}
__device__ __forceinline__ float bf2f(u16 u){ return __uint_as_float(((u32)u)<<16); }
__device__ __forceinline__ u16 f2bf(float f){            // exact RNE (cold paths)
  u32 u = __float_as_uint(f);
  u += 0x7fffu + ((u>>16)&1u);
  return (u16)(u>>16);
}
__device__ __forceinline__ u32 pk2bf(f32x2 v){
#if defined(__has_builtin) && __has_builtin(__builtin_amdgcn_cvt_pk_bf16_f32)
  auto r = __builtin_amdgcn_cvt_pk_bf16_f32(v.x, v.y);
  u32 u; __builtin_memcpy(&u, &r, 4); return u;
#else
  return ((__float_as_uint(v.x)+0x8000u)>>16) | ((__float_as_uint(v.y)+0x8000u) & 0xffff0000u);
#endif
}
__device__ __forceinline__ f32x2 upk2(u32 d){
  return f32x2{ __uint_as_float(d<<16), __uint_as_float(d & 0xffff0000u) };
}
template<bool F32>
__device__ __forceinline__ float ldv(const void* p, int i){
  if (F32) return ((const float*)p)[i];
  return bf2f(((const u16*)p)[i]);
}
template<bool F32>
__device__ __forceinline__ u16 ldbf(const void* p, int i){
  if (F32) return f2bf(((const float*)p)[i]);
  return ((const u16*)p)[i];
}
__device__ __forceinline__ bf16x8 cat44(bf16x4 lo, bf16x4 hi){
  bf16x8 r = {lo[0],lo[1],lo[2],lo[3],hi[0],hi[1],hi[2],hi[3]};
  return r;
}
__device__ __forceinline__ bf16x8 mk8(u32 a0, u32 a1, u32 a2, u32 a3){
  u32 t[4] = {a0,a1,a2,a3};
  bf16x8 r; __builtin_memcpy(&r, t, 16); return r;
}
// packed silu -> bf16 pair; arith f32x2 (v_pk_*_f32), trans scalar
__device__ __forceinline__ u32 spk(f32x2 z){
  const f32x2 nl2e2 = {-L2E, -L2E};
  const f32x2 one2  = {1.f, 1.f};
  f32x2 a = z * nl2e2;
  f32x2 e = { __builtin_amdgcn_exp2f(a.x), __builtin_amdgcn_exp2f(a.y) };
  f32x2 d = one2 + e;
  f32x2 rc = { __builtin_amdgcn_rcpf(d.x), __builtin_amdgcn_rcpf(d.y) };
  f32x2 s = z * rc;
  return pk2bf(s);
}

__device__ __forceinline__ int sniff_bf16(const void* tok_emb, int tid){
  int sane = 0;
  if (tid < 64){
    u16 wd = ((const u16*)tok_emb)[tid];
    int e = (wd >> 7) & 0xFF;
    sane = (e >= 100 && e <= 140) ? 1 : 0;
  }
  return (__syncthreads_count(sane) >= 52) ? 1 : 0;
}

// ===== pre-kernel 1: weight fragments (grid 288 x 64) =====
// input (embedding) rows of wq/wk/wvo/w1 stored pi-permuted:
//   k-slot (quad, j) carries embedding pr = quad*4 + (j&3) + 16*(j>=4)
// wq pre-scaled by QCE. w2 keeps the r13 C-quad-pair hidden k-order.
template<bool F32>
__device__ __forceinline__ void frag_body(const void* wq, const void* wk,
    const void* wv, const void* wo, const void* w1, const void* w2, void* ws)
{
  int t = blockIdx.x;
  int l = t / 72, k = t % 72;
  int lane = threadIdx.x, l16 = lane & 15, quad = lane >> 4;
  bf16x8 v;
  if (k < 8){
    int mat = k >> 1, half = k & 1;
    if (mat == 2){
      // wvo = wv @ wo  (f32 accumulate, single bf16 rounding); pi on wv rows
      int col = half*16 + l16;
      #pragma unroll
      for (int j=0;j<8;j++){
        int pr = quad*4 + (j&3) + ((j&4)<<2);
        float acc = 0.f;
        for (int e=0;e<EE;e++)
          acc += ldv<F32>(wv, l*1024 + pr*32 + e) * ldv<F32>(wo, l*1024 + e*32 + col);
        v[j] = (short)f2bf(acc);
      }
    } else if (mat == 0){
      #pragma unroll
      for (int j=0;j<8;j++){
        int pr = quad*4 + (j&3) + ((j&4)<<2);
        v[j] = (short)f2bf(QCE * ldv<F32>(wq, l*1024 + pr*32 + half*16 + l16));
      }
    } else {
      const void* src = (mat==1)? wk : wo;
      #pragma unroll
      for (int j=0;j<8;j++){
        int pr = quad*4 + (j&3) + ((j&4)<<2);
        v[j] = (short)ldbf<F32>(src, l*1024 + pr*32 + half*16 + l16);
      }
    }
  } else if (k < 40){
    int nt = k - 8;
    #pragma unroll
    for (int j=0;j<8;j++){
      int pr = quad*4 + (j&3) + ((j&4)<<2);
      v[j] = (short)ldbf<F32>(w1, l*16384 + pr*512 + nt*16 + l16);
    }
  } else {
    int kc = (k-40)>>1, nh = (k-40)&1;
    #pragma unroll
    for (int j=0;j<8;j++){
      int hh = kc*32 + ((j&4) ? 16 : 0) + quad*4 + (j&3);
      v[j] = (short)ldbf<F32>(w2, l*16384 + hh*32 + nh*16 + l16);
    }
  }
  *(bf16x8*)((char*)ws + WS_FRAG + t*1024 + lane*16) = v;
}

__global__ __launch_bounds__(64) void fmt_frags(
    const void* __restrict__ tok_emb,
    const void* __restrict__ wq, const void* __restrict__ wk,
    const void* __restrict__ wv, const void* __restrict__ wo,
    const void* __restrict__ w1, const void* __restrict__ w2,
    void* __restrict__ ws)
{
  if (sniff_bf16(tok_emb, threadIdx.x)) frag_body<false>(wq,wk,wv,wo,w1,w2,ws);
  else                                  frag_body<true >(wq,wk,wv,wo,w1,w2,ws);
}

// ===== pre-kernel 2: biases / LN / head params (unchanged layouts) =====
template<bool F32>
__device__ __forceinline__ void bias_body(
    const void* bq, const void* bk, const void* bv, const void* wo, const void* bo,
    const void* ln1_g, const void* ln1_b, const void* ln2_g, const void* ln2_b,
    const void* b1, const void* b2,
    const void* lnf_g, const void* lnf_b, const void* wpen, const void* bpen,
    const void* wfan, const void* bfan, const void* wcal, const void* bcal,
    void* ws)
{
  int tid = threadIdx.x, idx = tid & 31, grp = tid >> 5;
  float* BW  = (float*)((char*)ws + WS_BIAS);
  float* BW1 = (float*)((char*)ws + WS_B1);
  float* FW  = (float*)((char*)ws + WS_FIN);
  for (int l=0;l<NTRL;l++){
    float v = 0.f;
    switch(grp){
      case 0: v = QCE * ldv<F32>(bq, l*32+idx); break;   // scaled with wq
      case 1: v = ldv<F32>(bk, l*32+idx); break;
      case 2: {
        float acc = ldv<F32>(bo, l*32+idx);
        for (int e=0;e<EE;e++) acc += ldv<F32>(bv, l*32+e) * ldv<F32>(wo, l*1024 + e*32 + idx);
        v = acc; break;
      }
      case 3: v = ldv<F32>(ln1_g, l*32+idx); break;
      case 4: v = ldv<F32>(ln1_b, l*32+idx); break;
      case 5: v = ldv<F32>(ln2_g, l*32+idx); break;
      case 6: v = ldv<F32>(ln2_b, l*32+idx); break;
      case 7: v = ldv<F32>(b2,   l*32+idx); break;
    }
    BW[l*256 + tid] = v;
  }
  for (int i=tid; i<NTRL*HIDN; i+=256) BW1[i] = ldv<F32>(b1, i);
  if (tid < 32){
    FW[tid]    = ldv<F32>(lnf_g, tid);
    FW[32+tid] = ldv<F32>(lnf_b, tid);
    FW[64+tid] = ldv<F32>(wpen, tid);
  }
  if (tid == 0) FW[96] = ldv<F32>(bpen, 0);
  if (tid < 16){ FW[97+tid] = ldv<F32>(wfan, tid); FW[113+tid] = ldv<F32>(bfan, tid); }
  if (tid < 128) FW[129+tid] = ldv<F32>(wcal, tid);
  if (tid < 8)   FW[257+tid] = ldv<F32>(bcal, tid);
}

__global__ __launch_bounds__(256) void fmt_bias(
    const void* __restrict__ tok_emb,
    const void* __restrict__ bq, const void* __restrict__ bk,
    const void* __restrict__ bv, const void* __restrict__ wo, const void* __restrict__ bo,
    const void* __restrict__ ln1_g, const void* __restrict__ ln1_b,
    const void* __restrict__ ln2_g, const void* __restrict__ ln2_b,
    const void* __restrict__ b1, const void* __restrict__ b2,
    const void* __restrict__ lnf_g, const void* __restrict__ lnf_b,
    const void* __restrict__ wpen, const void* __restrict__ bpen,
    const void* __restrict__ wfan, const void* __restrict__ bfan,
    const void* __restrict__ wcal, const void* __restrict__ bcal,
    void* __restrict__ ws)
{
  if (sniff_bf16(tok_emb, threadIdx.x))
    bias_body<false>(bq,bk,bv,wo,bo,ln1_g,ln1_b,ln2_g,ln2_b,b1,b2,
                     lnf_g,lnf_b,wpen,bpen,wfan,bfan,wcal,bcal,ws);
  else
    bias_body<true >(bq,bk,bv,wo,bo,ln1_g,ln1_b,ln2_g,ln2_b,b1,b2,
                     lnf_g,lnf_b,wpen,bpen,wfan,bfan,wcal,bcal,ws);
}

// ===== main kernel helpers =====
// LN-normalize the lane's 8 owned X values (packed bf16, BY VALUE) into a frag.
__device__ __forceinline__ bf16x8 nfrag_x(u32x4 x, float m, float rs,
                                          f32x4 ga, f32x4 gb, f32x4 ba, f32x4 bb){
  f32x2 m2 = {m, m}, rs2 = {rs, rs};
  u32 o0 = pk2bf((upk2(x[0]) - m2) * rs2 * f32x2{ga[0],ga[1]} + f32x2{ba[0],ba[1]});
  u32 o1 = pk2bf((upk2(x[1]) - m2) * rs2 * f32x2{ga[2],ga[3]} + f32x2{ba[2],ba[3]});
  u32 o2 = pk2bf((upk2(x[2]) - m2) * rs2 * f32x2{gb[0],gb[1]} + f32x2{bb[0],bb[1]});
  u32 o3 = pk2bf((upk2(x[3]) - m2) * rs2 * f32x2{gb[2],gb[3]} + f32x2{bb[2],bb[3]});
  return mk8(o0, o1, o2, o3);
}

// reduce per-quad partials (8 cols each) to full-row mean/rsqrt in registers
__device__ __forceinline__ void red_stats(float ps, float pq, float& m, float& rs){
  ps += __shfl_xor(ps, 16); ps += __shfl_xor(ps, 32);
  pq += __shfl_xor(pq, 16); pq += __shfl_xor(pq, 32);
  m  = ps * (1.f/EE);
  rs = rsqrtf(pq * (1.f/EE) - m*m + 1e-5f);
}

template<bool F32>
__device__ __forceinline__ void tr_body(
    const int* seq, const int* expid,
    const void* tok_emb, const void* pos_emb,
    const void* ws, void* out, unsigned char* smem)
{
  u32* K2  = (u32*)smem;               // 208 rows x 20 u32 (pair-interleaved K)
  u16* VW2 = (u16*)(smem + VW2_OFF);   // 32 rows x 216 u16 (block-interleaved)

  const int tid  = threadIdx.x;
  const int lane = tid & 63, w = tid >> 6;
  const int l16  = lane & 15, quad = lane >> 4;
  const int b    = blockIdx.x;
  const f32x4 Z  = {0.f,0.f,0.f,0.f};

  // ---- embedding + positional straight into registers (pi-order) ----
  u32x4 xp[4];
  float m1[4], rs1[4], m2v[4], rs2v[4];
  {
    const int* srow = seq + b*SS;
    #pragma unroll
    for (int t=0;t<4;t++){
      int m = w + 4*t;
      if (m < NMT){
        int row = m*16 + l16;
        if (row < SS){
          int tok = srow[row];
          #pragma unroll
          for (int p=0;p<4;p++){
            int c = (p<2) ? (quad*4 + 2*p) : (16 + quad*4 + 2*(p-2));
            f32x2 v = { ldv<F32>(tok_emb, tok*EE + c)   + ldv<F32>(pos_emb, row*EE + c),
                        ldv<F32>(tok_emb, tok*EE + c+1) + ldv<F32>(pos_emb, row*EE + c+1) };
            xp[t][p] = pk2bf(v);
          }
        } else {
          xp[t] = u32x4{0u,0u,0u,0u};
        }
        f32x2 s2 = {0.f,0.f}, q2 = {0.f,0.f};
        #pragma unroll
        for (int p=0;p<4;p++){ f32x2 x = upk2(xp[t][p]); s2 += x; q2 += x*x; }
        red_stats(s2.x+s2.y, q2.x+q2.y, m1[t], rs1[t]);
      }
    }
  }

  for (int l = 0; l < NTRL; ++l){
    const char* wsl = (const char*)ws + WS_FRAG + l*73728;
    const float* BW = (const float*)((const char*)ws + WS_BIAS) + l*256;
    bf16x8 bwq0 = *(const bf16x8*)(wsl + 0*1024 + lane*16);
    bf16x8 bwq1 = *(const bf16x8*)(wsl + 1*1024 + lane*16);
    bf16x8 bwk0 = *(const bf16x8*)(wsl + 2*1024 + lane*16);
    bf16x8 bwk1 = *(const bf16x8*)(wsl + 3*1024 + lane*16);
    bf16x8 bwv0 = *(const bf16x8*)(wsl + 4*1024 + lane*16);  // wvo halves
    bf16x8 bwv1 = *(const bf16x8*)(wsl + 5*1024 + lane*16);

    // ===== Phase B: K2, VW2 to LDS; Q^T packed in-register =====
    bf16x8 aq[4];
    {
      f32x4 ga = *(const f32x4*)(BW + 96 + quad*4);
      f32x4 gb = *(const f32x4*)(BW + 112 + quad*4);
      f32x4 ba = *(const f32x4*)(BW + 128 + quad*4);
      f32x4 bb = *(const f32x4*)(BW + 144 + quad*4);
      f32x4 bq0 = *(const f32x4*)(BW + quad*4);        // pre-scaled by QCE
      f32x4 bq1 = *(const f32x4*)(BW + 16 + quad*4);
      float bk0s = BW[32+l16], bk1s = BW[48+l16];
      f32x4 kc0 = {bk0s,bk0s,bk0s,bk0s};
      f32x4 kc1 = {bk1s,bk1s,bk1s,bk1s};
      #pragma unroll
      for (int t=0;t<4;t++){
        int m = w + 4*t;
        if (m < NMT){
          int m16 = m*16;
          bf16x8 an = nfrag_x(xp[t], m1[t], rs1[t], ga, gb, ba, bb);
          f32x4 ck0 = MF(an, bwk0, kc0), ck1 = MF(an, bwk1, kc1);
          #pragma unroll
          for (int r=0;r<4;r++)
            K2[(m16 + quad*4 + r)*K2ST + l16] = pk2bf(f32x2{ck0[r], ck1[r]});
          f32x4 cw0 = MF(an, bwv0, Z), cw1 = MF(an, bwv1, Z);
          {
            // block-interleave: pair p=m>>1 at u16 col p*32 + quad*8 + (m&1)*4;
            // tile 12 plain at 192 + quad*4. Contiguous r -> merged b64 writes.
            int base = (m == 12) ? (192 + quad*4)
                                 : ((m>>1)*32 + quad*8 + (m&1)*4);
            u32* p0 = (u32*)(VW2 + l16*VWST + base);
            u32* p1 = (u32*)(VW2 + (16+l16)*VWST + base);
            p0[0] = pk2bf(f32x2{cw0[0], cw0[1]});
            p0[1] = pk2bf(f32x2{cw0[2], cw0[3]});
            p1[0] = pk2bf(f32x2{cw1[0], cw1[1]});
            p1[1] = pk2bf(f32x2{cw1[2], cw1[3]});
          }
          f32x4 cq0 = MF(bwq0, an, bq0), cq1 = MF(bwq1, an, bq1);
          aq[t] = mk8(pk2bf(f32x2{cq0[0],cq1[0]}), pk2bf(f32x2{cq0[1],cq1[1]}),
                      pk2bf(f32x2{cq0[2],cq1[2]}), pk2bf(f32x2{cq0[3],cq1[3]}));
        }
      }
    }
    __syncthreads();   // K2/VW2 ready for all waves

    // ===== Phase C: attention via S^T + fused LN2 stats (register X RMW) =====
    {
      const u16* vb0 = VW2 + l16*VWST;
      const u16* vb1 = VW2 + (16+l16)*VWST;
      f32x4 ob0 = *(const f32x4*)(BW + 64 + quad*4);
      f32x4 ob1 = *(const f32x4*)(BW + 80 + quad*4);
      #pragma unroll
      for (int t=0;t<4;t++){
        int m = w + 4*t;
        if (m < NMT){
          u32 pbw[7][4];
          f32x2 pacc = {0.f, 0.f};
          #pragma unroll
          for (int c=0;c<6;c++){
            const bf16x8 ka = *(const bf16x8*)(K2 + ((2*c  )*16+l16)*K2ST + quad*4);
            const bf16x8 kb = *(const bf16x8*)(K2 + ((2*c+1)*16+l16)*K2ST + quad*4);
            f32x4 S0 = MF(ka, aq[t], Z);
            f32x4 S1 = MF(kb, aq[t], Z);
            f32x2 ea0 = { __builtin_amdgcn_exp2f(S0[0]), __builtin_amdgcn_exp2f(S0[1]) };
            f32x2 eb0 = { __builtin_amdgcn_exp2f(S0[2]), __builtin_amdgcn_exp2f(S0[3]) };
            f32x2 ea1 = { __builtin_amdgcn_exp2f(S1[0]), __builtin_amdgcn_exp2f(S1[1]) };
            f32x2 eb1 = { __builtin_amdgcn_exp2f(S1[2]), __builtin_amdgcn_exp2f(S1[3]) };
            pacc += (ea0 + eb0) + (ea1 + eb1);
            // BLOCK k-order: j0..3 = tile 2c keys q4..+3, j4..7 = tile 2c+1
            pbw[c][0] = pk2bf(ea0);
            pbw[c][1] = pk2bf(eb0);
            pbw[c][2] = pk2bf(ea1);
            pbw[c][3] = pk2bf(eb1);
          }
          { // tail: tile 12, keys 192..207 (201..207 masked)
            const bf16x8 ka = *(const bf16x8*)(K2 + (12*16+l16)*K2ST + quad*4);
            f32x4 S0 = MF(ka, aq[t], Z);
            f32x2 ea0 = { __builtin_amdgcn_exp2f(S0[0]), __builtin_amdgcn_exp2f(S0[1]) };
            f32x2 eb0 = { __builtin_amdgcn_exp2f(S0[2]), __builtin_amdgcn_exp2f(S0[3]) };
            int kb_ = quad*4;                 // keys 201..207: local idx >= 9
            if (kb_+0 >= 9) ea0.x = 0.f;
            if (kb_+1 >= 9) ea0.y = 0.f;
            if (kb_+2 >= 9) eb0.x = 0.f;
            if (kb_+3 >= 9) eb0.y = 0.f;
            pacc += ea0 + eb0;
            pbw[6][0] = pk2bf(ea0);
            pbw[6][1] = pk2bf(eb0);
            pbw[6][2] = 0u;
            pbw[6][3] = 0u;
          }
          float part = pacc.x + pacc.y;
          part += __shfl_xor(part, 16);
          part += __shfl_xor(part, 32);
          float inv = __builtin_amdgcn_rcpf(part);   // per query l16

          // PV: O^T = VW^T . P^T; block-interleaved b128 A-reads, tail dup
          f32x4 o0 = Z, o1 = Z;
          #pragma unroll
          for (int c=0;c<6;c++){
            bf16x8 A0 = *(const bf16x8*)(vb0 + c*32 + quad*8);
            bf16x8 A1 = *(const bf16x8*)(vb1 + c*32 + quad*8);
            bf16x8 B8 = mk8(pbw[c][0], pbw[c][1], pbw[c][2], pbw[c][3]);
            o0 = MF(A0, B8, o0);
            o1 = MF(A1, B8, o1);
          }
          {
            bf16x4 a0 = *(const bf16x4*)(vb0 + 192 + quad*4);
            bf16x4 a1 = *(const bf16x4*)(vb1 + 192 + quad*4);
            bf16x8 B8 = mk8(pbw[6][0], pbw[6][1], 0u, 0u);
            o0 = MF(cat44(a0, a0), B8, o0);   // upper A pairs with zero B
            o1 = MF(cat44(a1, a1), B8, o1);
          }

          // register X RMW + fused LN2 stats (pre-rounding f32 values)
          f32x2 r01 = f32x2{o0[0],o0[1]} * inv + (upk2(xp[t][0]) + f32x2{ob0[0],ob0[1]});
          f32x2 r23 = f32x2{o0[2],o0[3]} * inv + (upk2(xp[t][1]) + f32x2{ob0[2],ob0[3]});
          f32x2 s01 = f32x2{o1[0],o1[1]} * inv + (upk2(xp[t][2]) + f32x2{ob1[0],ob1[1]});
          f32x2 s23 = f32x2{o1[2],o1[3]} * inv + (upk2(xp[t][3]) + f32x2{ob1[2],ob1[3]});
          xp[t][0] = pk2bf(r01);
          xp[t][1] = pk2bf(r23);
          xp[t][2] = pk2bf(s01);
          xp[t][3] = pk2bf(s23);
          f32x2 ss = (r01 + r23) + (s01 + s23);
          f32x2 qq = r01*r01; qq += r23*r23; qq += s01*s01; qq += s23*s23;
          red_stats(ss.x+ss.y, qq.x+qq.y, m2v[t], rs2v[t]);
        }
      }
    }
    __syncthreads();   // all K2/VW2 reads done; next-layer B may overwrite

    // ===== Phase E: MLP register-resident, register X RMW, fused LN1 stats =====
    {
      f32x4 ga = *(const f32x4*)(BW + 160 + quad*4);
      f32x4 gb = *(const f32x4*)(BW + 176 + quad*4);
      f32x4 ba = *(const f32x4*)(BW + 192 + quad*4);
      f32x4 bb = *(const f32x4*)(BW + 208 + quad*4);
      bf16x8 anc[4];
      #pragma unroll
      for (int t=0;t<4;t++){
        int m = w + 4*t;
        if (m < NMT) anc[t] = nfrag_x(xp[t], m2v[t], rs2v[t], ga, gb, ba, bb);
      }
      f32x4 oacc[4][2];
      #pragma unroll
      for (int t=0;t<4;t++){ oacc[t][0] = Z; oacc[t][1] = Z; }
      const char* w1f = wsl + 8*1024;
      const char* w2f = wsl + 40*1024;
      const float* BW1 = (const float*)((const char*)ws + WS_B1) + l*HIDN;

      for (int hp = 0; hp < 16; ++hp){
        bf16x8 a1lo = *(const bf16x8*)(w1f + (2*hp  )*1024 + lane*16);
        bf16x8 a1hi = *(const bf16x8*)(w1f + (2*hp+1)*1024 + lane*16);
        bf16x8 a2e0 = *(const bf16x8*)(w2f + (hp*2  )*1024 + lane*16);
        bf16x8 a2e1 = *(const bf16x8*)(w2f + (hp*2+1)*1024 + lane*16);
        f32x4 b1q0 = *(const f32x4*)(BW1 + hp*32      + quad*4);
        f32x4 b1q1 = *(const f32x4*)(BW1 + hp*32 + 16 + quad*4);
        #pragma unroll
        for (int t=0;t<4;t++){
          int m = w + 4*t;
          if (m < NMT){
            f32x4 z0 = MF(a1lo, anc[t], b1q0);   // bias in C (exact)
            f32x4 z1 = MF(a1hi, anc[t], b1q1);
            bf16x8 H8 = mk8(spk(f32x2{z0[0], z0[1]}), spk(f32x2{z0[2], z0[3]}),
                            spk(f32x2{z1[0], z1[1]}), spk(f32x2{z1[2], z1[3]}));
            oacc[t][0] = MF(a2e0, H8, oacc[t][0]);
            oacc[t][1] = MF(a2e1, H8, oacc[t][1]);
          }
        }
      }

      f32x4 b2q0 = *(const f32x4*)(BW + 224 + quad*4);
      f32x4 b2q1 = *(const f32x4*)(BW + 240 + quad*4);
      #pragma unroll
      for (int t=0;t<4;t++){
        int m = w + 4*t;
        if (m < NMT){
          f32x2 r01 = f32x2{oacc[t][0][0], oacc[t][0][1]} + (upk2(xp[t][0]) + f32x2{b2q0[0], b2q0[1]});
          f32x2 r23 = f32x2{oacc[t][0][2], oacc[t][0][3]} + (upk2(xp[t][1]) + f32x2{b2q0[2], b2q0[3]});
          f32x2 s01 = f32x2{oacc[t][1][0], oacc[t][1][1]} + (upk2(xp[t][2]) + f32x2{b2q1[0], b2q1[1]});
          f32x2 s23 = f32x2{oacc[t][1][2], oacc[t][1][3]} + (upk2(xp[t][3]) + f32x2{b2q1[2], b2q1[3]});
          xp[t][0] = pk2bf(r01);
          xp[t][1] = pk2bf(r23);
          xp[t][2] = pk2bf(s01);
          xp[t][3] = pk2bf(s23);
          f32x2 ss = (r01 + r23) + (s01 + s23);
          f32x2 qq = r01*r01; qq += r23*r23; qq += s01*s01; qq += s23*s23;
          red_stats(ss.x+ss.y, qq.x+qq.y, m1[t], rs1[t]);
        }
      }
    }
    // no barrier: E touches only registers + globals; next-layer B's LDS
    // writes are fenced by the post-C barrier above.
  }

  // ===== final head =====
  const float* FW = (const float*)((const char*)ws + WS_FIN);
  float* HB = (float*)(smem + VW2_OFF);        // VW2 region free after last C
  if (tid < 32){
    HB[tid]    = FW[tid];
    HB[32+tid] = FW[32+tid];
    HB[64+tid] = FW[64+tid];
  }
  // dump X registers (K2 region free after last C), stride 18 u32
  u32* hd = (u32*)smem;
  #pragma unroll
  for (int t=0;t<4;t++){
    int m = w + 4*t;
    if (m < NMT){
      u32* hr = hd + (m*16 + l16)*18;
      hr[quad*2]     = xp[t][0];
      hr[quad*2+1]   = xp[t][1];
      hr[8+quad*2]   = xp[t][2];
      hr[8+quad*2+1] = xp[t][3];
    }
  }
  __syncthreads();
  float part = 0.f;
  if (tid < SS){
    const u32* row = hd + tid*18;
    f32x2 v[16]; f32x2 s2 = {0.f,0.f};
    #pragma unroll
    for (int i=0;i<16;i++){ f32x2 p = upk2(row[i]); v[i] = p; s2 += p; }
    float m = (s2.x+s2.y) * (1.f/EE);
    f32x2 m2 = {m,m};
    f32x2 var2 = {0.f,0.f};
    #pragma unroll
    for (int i=0;i<16;i++){ f32x2 d = v[i]-m2; var2 += d*d; }
    float rs = rsqrtf((var2.x+var2.y)*(1.f/EE) + 1e-5f);
    f32x2 rs2 = {rs, rs};
    f32x2 dot2 = {0.f,0.f};
    #pragma unroll
    for (int i=0;i<16;i++){
      f32x2 g  = {HB[2*i], HB[2*i+1]};
      f32x2 bb = {HB[32+2*i], HB[33+2*i]};
      f32x2 wp = {HB[64+2*i], HB[65+2*i]};
      dot2 += ((v[i]-m2)*rs2*g + bb) * wp;
    }
    part = dot2.x + dot2.y + FW[96];
  }
  #pragma unroll
  for (int off=32; off; off>>=1) part += __shfl_xor(part, off);
  float* REDF = (float*)(smem + VW2_OFF + 512);
  __syncthreads();
  if (lane == 0) REDF[w] = part;
  __syncthreads();
  if (tid == 0){
    float u = REDF[0] + REDF[1] + REDF[2] + REDF[3];
    int ex = expid[b];
    float corr = FW[257+ex];
    #pragma unroll
    for (int c = 0; c < CWN; ++c){
      float pre = u * FW[97+c] + FW[113+c];
      pre = pre > 0.f ? pre : (__expf(pre) - 1.f);
      corr += pre * FW[129 + ex*CWN + c];
    }
    float res = corr + u;
    if (F32) ((float*)out)[b] = res;
    else     ((u16*)out)[b]  = f2bf(res);
  }
}

__global__ __launch_bounds__(256, 3) void tr_kernel(
    const int* __restrict__ seq, const int* __restrict__ expid,
    const void* __restrict__ tok_emb, const void* __restrict__ pos_emb,
    const void* __restrict__ ws, void* __restrict__ out)
{
  __shared__ __align__(16) unsigned char smem[SMEM_SZ];
  if (sniff_bf16(tok_emb, threadIdx.x))
    tr_body<false>(seq, expid, tok_emb, pos_emb, ws, out, smem);
  else
    tr_body<true >(seq, expid, tok_emb, pos_emb, ws, out, smem);
}

extern "C" void kernel_launch(void* const* d_in, const int* in_sizes, int n_in,
                              void* d_out, int out_size, void* d_ws, size_t ws_size,
                              hipStream_t stream)
{
  (void)in_sizes; (void)n_in; (void)ws_size; (void)out_size;
  const void* tok_emb = d_in[2];
  fmt_frags<<<dim3(288), dim3(64), 0, stream>>>(
      tok_emb, d_in[6], d_in[7], d_in[8], d_in[12], d_in[16], d_in[18], d_ws);
  fmt_bias<<<dim3(1), dim3(256), 0, stream>>>(
      tok_emb, d_in[9], d_in[10], d_in[11], d_in[12], d_in[13],
      d_in[4], d_in[5], d_in[14], d_in[15], d_in[17], d_in[19],
      d_in[20], d_in[21], d_in[22], d_in[23],
      d_in[24], d_in[25], d_in[26], d_in[27], d_ws);
  tr_kernel<<<dim3(BB), dim3(256), 0, stream>>>(
      (const int*)d_in[0], (const int*)d_in[1], tok_emb, d_in[3], d_ws, d_out);
}